// Round 3
// baseline (437.897 us; speedup 1.0000x reference)
//
#include <hip/hip_runtime.h>
#include <cstddef>

#define NSTATES 32
#define SEQLEN 4096
#define NBATCH 256
#define CHUNK_L 256
#define HALO 96
#define NCHUNKS (SEQLEN / CHUNK_L)   // 16
#define WPB 4                        // waves per block
#define XBUF_LEN (CHUNK_L + HALO)    // 352

#define F_LOG2E 1.44269504088896340736f
#define F_LN2   0.69314718055994530942f
#define F_NEG_HALF_LOG2PI -0.91893853320467274178f

#define EXP2F(x) __builtin_amdgcn_exp2f(x)
#define LOG2F(x) __builtin_amdgcn_logf(x)   // v_log_f32 == log2, despite the name

static __device__ __forceinline__ float wmax32(float v) {
#pragma unroll
    for (int m = 16; m >= 1; m >>= 1) v = fmaxf(v, __shfl_xor(v, m, 64));
    return v;
}
static __device__ __forceinline__ float wsum32(float v) {
#pragma unroll
    for (int m = 16; m >= 1; m >>= 1) v += __shfl_xor(v, m, 64);
    return v;
}

// One recursion step's logmatexp core (base-2, normalized input vin):
//   returns log2( sum_j A[i][j] * 2^(vin_j - max(vin)) )
// Shift-invariance of the whole recursion lets us drop the "+max" term;
// f/b stay bounded so fp32 exp/log are always in range.
#define STEP_BODY(vin, result)                                            \
    {                                                                     \
        float m_ = wmax32(vin);                                           \
        float p_ = EXP2F((vin) - m_);                                     \
        psp[i] = p_;                                                      \
        __threadfence_block(); /* in-wave LDS write->read ordering */     \
        float ax = 0.f, ay = 0.f, az = 0.f, aw = 0.f;                     \
        _Pragma("unroll")                                                 \
        for (int jj = 0; jj < 8; ++jj) {                                  \
            float4 pv = ps4[jj];                                          \
            ax = fmaf(arow[jj].x, pv.x, ax);                              \
            ay = fmaf(arow[jj].y, pv.y, ay);                              \
            az = fmaf(arow[jj].z, pv.z, az);                              \
            aw = fmaf(arow[jj].w, pv.w, aw);                              \
        }                                                                 \
        __threadfence_block(); /* reads before next iteration's write */  \
        result = LOG2F((ax + ay) + (az + aw));                            \
    }

__global__ __launch_bounds__(WPB * 64) void hmm_fwd(
    const float* __restrict__ obvs,
    const float* __restrict__ log_init,
    const float* __restrict__ Amat,
    const float* __restrict__ means,
    const float* __restrict__ log_sig,
    float* __restrict__ fbuf)
{
    __shared__ float xs[WPB][2][XBUF_LEN];
    __shared__ __align__(16) float ps[WPB][2][NSTATES];

    const int tid  = threadIdx.x;
    const int w    = tid >> 6;
    const int lane = tid & 63;
    const int h    = lane >> 5;
    const int i    = lane & 31;

    const int wgid  = blockIdx.x * WPB + w;       // 0..2047
    const int chunk = wgid >> 7;                  // 0..15 (uniform per wave)
    const int row   = ((wgid & 127) << 1) | h;    // 0..255

    const int t0 = chunk * CHUNK_L;
    const int t1 = t0 + CHUNK_L;
    const int ts = (chunk == 0) ? 0 : t0 - HALO;

    // per-state emission constants, base-2 folded
    const float mu   = means[i];
    const float lsig = log_sig[i];
    const float c1   = -0.5f * expf(-2.0f * lsig) * F_LOG2E;
    const float c0   = (-lsig + F_NEG_HALF_LOG2PI) * F_LOG2E;
    const float li2  = log_init[i] * F_LOG2E;

    // A row i in registers (linear-space transition row)
    float4 arow[8];
#pragma unroll
    for (int jj = 0; jj < 8; ++jj)
        arow[jj] = reinterpret_cast<const float4*>(Amat)[i * 8 + jj];

    // stage obvs[row][ts..t1) into LDS
    const float* xr = obvs + (size_t)row * SEQLEN;
    for (int t = ts + i; t < t1; t += 32) xs[w][h][t - ts] = xr[t];
    __syncthreads();

    const float* xp = &xs[w][h][0];
    float* psp = &ps[w][h][0];
    const float4* ps4 = reinterpret_cast<const float4*>(psp);

#define E2(x) ({ float d_ = (x) - mu; fmaf(d_ * d_, c1, c0); })

    float* frow = fbuf + (size_t)row * SEQLEN * NSTATES + i;

    float f = E2(xp[0]);
    if (chunk == 0) {
        f += li2;
        frow[0] = f;   // exact f[0]
    }

    // warm-up (empty for chunk 0)
    for (int t = ts + 1; t < t0; ++t) {
        float l; STEP_BODY(f, l);
        f = E2(xp[t - ts]) + l;
    }
    // main span: compute and store normalized f[t]
    const int tm = (chunk == 0) ? 1 : t0;
    for (int t = tm; t < t1; ++t) {
        float l; STEP_BODY(f, l);
        f = E2(xp[t - ts]) + l;
        frow[(size_t)t * NSTATES] = f;
    }
#undef E2
}

__global__ __launch_bounds__(WPB * 64) void hmm_bwd(
    const float* __restrict__ obvs,
    const float* __restrict__ log_init,
    const float* __restrict__ Amat,
    const float* __restrict__ means,
    const float* __restrict__ log_sig,
    float* __restrict__ io)   // reads f, writes normalized log_gamma in place
{
    __shared__ float xs[WPB][2][XBUF_LEN];
    __shared__ __align__(16) float ps[WPB][2][NSTATES];

    const int tid  = threadIdx.x;
    const int w    = tid >> 6;
    const int lane = tid & 63;
    const int h    = lane >> 5;
    const int i    = lane & 31;

    const int wgid  = blockIdx.x * WPB + w;
    const int chunk = wgid >> 7;
    const int row   = ((wgid & 127) << 1) | h;

    const int t0  = chunk * CHUNK_L;
    const int t1  = t0 + CHUNK_L;
    const int tsb = (t1 - 1 + HALO < SEQLEN - 1) ? (t1 - 1 + HALO) : (SEQLEN - 1);
    const int xbase = t0 + 1;   // xs slot for time t is t - xbase; need t in [t0+1, tsb]

    const float mu   = means[i];
    const float lsig = log_sig[i];
    const float c1   = -0.5f * expf(-2.0f * lsig) * F_LOG2E;
    const float c0   = (-lsig + F_NEG_HALF_LOG2PI) * F_LOG2E;
    const float li2  = log_init[i] * F_LOG2E;

    float4 arow[8];
#pragma unroll
    for (int jj = 0; jj < 8; ++jj)
        arow[jj] = reinterpret_cast<const float4*>(Amat)[i * 8 + jj];

    const float* xr = obvs + (size_t)row * SEQLEN;
    for (int t = xbase + i; t <= tsb; t += 32) xs[w][h][t - xbase] = xr[t];
    __syncthreads();

    const float* xp = &xs[w][h][0];
    float* psp = &ps[w][h][0];
    const float4* ps4 = reinterpret_cast<const float4*>(psp);

#define E2(x) ({ float d_ = (x) - mu; fmaf(d_ * d_, c1, c0); })

    float* frow = io + (size_t)row * SEQLEN * NSTATES + i;

#define COMBINE_STORE(t, bval)                                            \
    {                                                                     \
        float fv = frow[(size_t)(t) * NSTATES];                           \
        float g  = fv + (bval);                                           \
        float gm = wmax32(g);                                             \
        float sp = EXP2F(g - gm);                                         \
        float ss = wsum32(sp);                                            \
        frow[(size_t)(t) * NSTATES] = (g - gm - LOG2F(ss)) * F_LN2;       \
    }

    float b;
    int thi;
    if (t1 == SEQLEN) {
        b = li2;                 // exact b[T-1] = log_initial_probs
        COMBINE_STORE(SEQLEN - 1, b);
        thi = SEQLEN - 2;
    } else {
        b = 0.f;                 // uniform start at tsb; halo contracts it
        for (int t = tsb - 1; t >= t1; --t) {
            float v = b + E2(xp[t + 1 - xbase]);
            STEP_BODY(v, b);
        }
        thi = t1 - 1;
    }

    for (int t = thi; t >= t0; --t) {
        float v = b + E2(xp[t + 1 - xbase]);
        STEP_BODY(v, b);
        COMBINE_STORE(t, b);
    }
#undef E2
#undef COMBINE_STORE
}

extern "C" void kernel_launch(void* const* d_in, const int* in_sizes, int n_in,
                              void* d_out, int out_size, void* d_ws, size_t ws_size,
                              hipStream_t stream) {
    const float* obvs     = (const float*)d_in[0];
    const float* log_init = (const float*)d_in[1];
    const float* Amat     = (const float*)d_in[2];
    const float* means    = (const float*)d_in[3];
    const float* log_sig  = (const float*)d_in[4];
    float* out = (float*)d_out;

    dim3 grid(NCHUNKS * (NBATCH / 2) / WPB);   // 512
    dim3 block(WPB * 64);                      // 256

    hipLaunchKernelGGL(hmm_fwd, grid, block, 0, stream,
                       obvs, log_init, Amat, means, log_sig, out);
    hipLaunchKernelGGL(hmm_bwd, grid, block, 0, stream,
                       obvs, log_init, Amat, means, log_sig, out);
}

// Round 4
// 231.238 us; speedup vs baseline: 1.8937x; 1.8937x over previous
//
#include <hip/hip_runtime.h>
#include <cstddef>

#define NSTATES 32
#define SEQLEN 4096
#define NBATCH 256
#define CHUNK_L 128
#define HALO 96
#define NCHUNKS (SEQLEN / CHUNK_L)   // 32
#define WPB 4                        // waves per block
#define XBUF_LEN (CHUNK_L + HALO)    // 224
#define WAVES_PER_CHUNK (NBATCH / 2) // 128

#define F_LOG2E 1.44269504088896340736f
#define F_LN2   0.69314718055994530942f
#define F_NEG_HALF_LOG2PI -0.91893853320467274178f

#define EXP2F(x) __builtin_amdgcn_exp2f(x)
#define LOG2F(x) __builtin_amdgcn_logf(x)   // v_log_f32 == log2, despite the name
#define RCPF(x)  __builtin_amdgcn_rcpf(x)

// float view of ds_swizzle (imm must be literal at call site)
#define SWZF(x, imm) __int_as_float(__builtin_amdgcn_ds_swizzle(__float_as_int(x), (imm)))

// DPP xor-lane helper (VALU pipe, no LDS)
template <int CTRL>
static __device__ __forceinline__ float dppf(float x) {
    return __int_as_float(__builtin_amdgcn_update_dpp(
        0, __float_as_int(x), CTRL, 0xF, 0xF, true));
}
// DPP ctrl codes: xor1 = quad_perm(1,0,3,2)=0xB1; xor2 = quad_perm(2,3,0,1)=0x4E;
// xor7 = row_half_mirror=0x141; xor15 = row_mirror=0x140. xor16 needs ds_swizzle.
static __device__ __forceinline__ float rmax32(float v) {
    v = fmaxf(v, dppf<0xB1>(v));
    v = fmaxf(v, dppf<0x4E>(v));
    v = fmaxf(v, dppf<0x141>(v));
    v = fmaxf(v, dppf<0x140>(v));
    v = fmaxf(v, SWZF(v, 0x401F));
    return v;
}
static __device__ __forceinline__ float rsum32(float v) {
    v += dppf<0xB1>(v);
    v += dppf<0x4E>(v);
    v += dppf<0x141>(v);
    v += dppf<0x140>(v);
    v += SWZF(v, 0x401F);
    return v;
}

// Linear-space matvec through LDS broadcast: u_i = sum_j A[i][j] * q_j.
// All 32 lanes of a half read the SAME address per ds_read_b128 -> broadcast, no conflicts.
#define MATVEC(qv, uout)                                                  \
    {                                                                     \
        psp[i] = (qv);                                                    \
        __threadfence_block();                                            \
        float ax = 0.f, ay = 0.f, az = 0.f, aw = 0.f;                     \
        _Pragma("unroll")                                                 \
        for (int jj = 0; jj < 8; ++jj) {                                  \
            float4 pv = ps4[jj];                                          \
            ax = fmaf(arow[jj].x, pv.x, ax);                              \
            ay = fmaf(arow[jj].y, pv.y, ay);                              \
            az = fmaf(arow[jj].z, pv.z, az);                              \
            aw = fmaf(arow[jj].w, pv.w, aw);                              \
        }                                                                 \
        __threadfence_block();                                            \
        (uout) = (ax + ay) + (az + aw);                                   \
    }

__global__ __launch_bounds__(WPB * 64) void hmm_fwd(
    const float* __restrict__ obvs,
    const float* __restrict__ log_init,
    const float* __restrict__ Amat,
    const float* __restrict__ means,
    const float* __restrict__ log_sig,
    float* __restrict__ fbuf)   // stores log2(F_t), arbitrary per-t shift
{
    __shared__ float xs[WPB][2][XBUF_LEN];
    __shared__ __align__(16) float ps[WPB][2][NSTATES];

    const int tid  = threadIdx.x;
    const int w    = tid >> 6;
    const int lane = tid & 63;
    const int h    = lane >> 5;
    const int i    = lane & 31;

    const int wgid  = blockIdx.x * WPB + w;          // 0..4095
    const int chunk = wgid >> 7;                     // 0..31 (uniform per wave)
    const int row   = ((wgid & 127) << 1) | h;       // 0..255

    const int t0 = chunk * CHUNK_L;
    const int t1 = t0 + CHUNK_L;
    const int ts = (chunk == 0) ? 0 : t0 - HALO;

    // per-state emission constants, base-2 folded: e2(x) = fmaf(d*d, c1, c0)
    const float mu   = means[i];
    const float lsig = log_sig[i];
    const float c1   = -0.5f * expf(-2.0f * lsig) * F_LOG2E;
    const float c0   = (-lsig + F_NEG_HALF_LOG2PI) * F_LOG2E;
    const float li2  = log_init[i] * F_LOG2E;

    float4 arow[8];
#pragma unroll
    for (int jj = 0; jj < 8; ++jj)
        arow[jj] = reinterpret_cast<const float4*>(Amat)[i * 8 + jj];

    const float* xr = obvs + (size_t)row * SEQLEN;
    for (int t = ts + i; t < t1; t += 32) xs[w][h][t - ts] = xr[t];
    __syncthreads();

    const float* xp = &xs[w][h][0];
    float* psp = &ps[w][h][0];
    const float4* ps4 = reinterpret_cast<const float4*>(psp);

#define E2(x) ({ float d_ = (x) - mu; fmaf(d_ * d_, c1, c0); })

    float* frow = fbuf + (size_t)row * SEQLEN * NSTATES + i;

    // init: q = linear F at t = ts
    float e0 = E2(xp[0]);
    float q;
    if (chunk == 0) {
        float v0 = e0 + li2;
        frow[0] = v0;          // exact log2(f0)
        q = EXP2F(v0);
    } else {
        q = EXP2F(e0);         // warm start; halo contracts it
    }

    for (int t = ts + 1; t < t1; ++t) {
        float u;
        MATVEC(q, u);
        float r  = RCPF(SWZF(u, 0x0000));   // lane0-of-32 broadcast renorm
        float E  = EXP2F(E2(xp[t - ts]));
        q = (u * r) * E;
        if (t >= t0) frow[(size_t)t * NSTATES] = LOG2F(q);
    }
#undef E2
}

__global__ __launch_bounds__(WPB * 64) void hmm_bwd(
    const float* __restrict__ obvs,
    const float* __restrict__ log_init,
    const float* __restrict__ Amat,
    const float* __restrict__ means,
    const float* __restrict__ log_sig,
    float* __restrict__ io)   // reads log2(F), writes normalized log_gamma in place
{
    __shared__ float xs[WPB][2][XBUF_LEN];
    __shared__ __align__(16) float ps[WPB][2][NSTATES];

    const int tid  = threadIdx.x;
    const int w    = tid >> 6;
    const int lane = tid & 63;
    const int h    = lane >> 5;
    const int i    = lane & 31;

    const int wgid  = blockIdx.x * WPB + w;
    const int chunk = wgid >> 7;
    const int row   = ((wgid & 127) << 1) | h;

    const int t0  = chunk * CHUNK_L;
    const int t1  = t0 + CHUNK_L;
    const bool last = (t1 == SEQLEN);
    const int tsb = last ? (SEQLEN - 1) : (t1 - 1 + HALO);
    const int xbase = t0 + 1;   // xs slot for time t is t - xbase; t in [t0+1, tsb]

    const float mu   = means[i];
    const float lsig = log_sig[i];
    const float c1   = -0.5f * expf(-2.0f * lsig) * F_LOG2E;
    const float c0   = (-lsig + F_NEG_HALF_LOG2PI) * F_LOG2E;
    const float li2  = log_init[i] * F_LOG2E;

    float4 arow[8];
#pragma unroll
    for (int jj = 0; jj < 8; ++jj)
        arow[jj] = reinterpret_cast<const float4*>(Amat)[i * 8 + jj];

    const float* xr = obvs + (size_t)row * SEQLEN;
    for (int t = xbase + i; t <= tsb; t += 32) xs[w][h][t - xbase] = xr[t];
    __syncthreads();

    const float* xp = &xs[w][h][0];
    float* psp = &ps[w][h][0];
    const float4* ps4 = reinterpret_cast<const float4*>(psp);

#define E2(x) ({ float d_ = (x) - mu; fmaf(d_ * d_, c1, c0); })

    float* frow = io + (size_t)row * SEQLEN * NSTATES + i;

    float u;      // linear B_t carry
    int thi;
    if (last) {
        // exact b[T-1] = log_init (base-2: li2); fuse combine at T-1
        float g = frow[(size_t)(SEQLEN - 1) * NSTATES] + li2;
        float m = rmax32(g);
        float s = rsum32(EXP2F(g - m));
        frow[(size_t)(SEQLEN - 1) * NSTATES] = (g - m - LOG2F(s)) * F_LN2;
        u = EXP2F(li2);
        thi = SEQLEN - 2;
    } else {
        u = 1.0f;              // uniform start at tsb; halo contracts it
        thi = tsb - 1;
    }

    for (int t = thi; t >= t0; --t) {
        const bool store = (t < t1);           // uniform per wave
        float fv;
        if (store) fv = frow[(size_t)t * NSTATES];   // prefetch before matvec
        float r = RCPF(SWZF(u, 0x0000));
        float E = EXP2F(E2(xp[t + 1 - xbase]));
        float q = (u * r) * E;
        MATVEC(q, u);
        if (store) {
            float g = fv + LOG2F(u);
            float m = rmax32(g);
            float s = rsum32(EXP2F(g - m));
            frow[(size_t)t * NSTATES] = (g - m - LOG2F(s)) * F_LN2;
        }
    }
#undef E2
}

extern "C" void kernel_launch(void* const* d_in, const int* in_sizes, int n_in,
                              void* d_out, int out_size, void* d_ws, size_t ws_size,
                              hipStream_t stream) {
    const float* obvs     = (const float*)d_in[0];
    const float* log_init = (const float*)d_in[1];
    const float* Amat     = (const float*)d_in[2];
    const float* means    = (const float*)d_in[3];
    const float* log_sig  = (const float*)d_in[4];
    float* out = (float*)d_out;

    dim3 grid(NCHUNKS * WAVES_PER_CHUNK / WPB);   // 1024
    dim3 block(WPB * 64);                         // 256

    hipLaunchKernelGGL(hmm_fwd, grid, block, 0, stream,
                       obvs, log_init, Amat, means, log_sig, out);
    hipLaunchKernelGGL(hmm_bwd, grid, block, 0, stream,
                       obvs, log_init, Amat, means, log_sig, out);
}

// Round 5
// 182.589 us; speedup vs baseline: 2.3983x; 1.2664x over previous
//
#include <hip/hip_runtime.h>
#include <cstddef>

#define NSTATES 32
#define SEQLEN 4096
#define NBATCH 256

#define F_LOG2E 1.44269504088896340736f
#define F_LN2   0.69314718055994530942f
#define F_NEG_HALF_LOG2PI -0.91893853320467274178f

#define EXP2F(x) __builtin_amdgcn_exp2f(x)
#define LOG2F(x) __builtin_amdgcn_logf(x)   // v_log_f32 == log2, despite the name
#define RCPF(x)  __builtin_amdgcn_rcpf(x)

typedef __attribute__((ext_vector_type(8)))  short short8;
typedef __attribute__((ext_vector_type(16))) float f32x16;

// ===================== MFMA path =====================
#define MF_CHUNK   32
#define MF_NCHUNK  128          // 4096/32
#define MF_HALO_F  96
#define MF_HALO_B  95
#define MF_SPANF   128
#define MF_SPANB   127

static __device__ __forceinline__ unsigned int pkbf(float lo, float hi) {
    unsigned int r;
    asm("v_cvt_pk_bf16_f32 %0, %1, %2" : "=v"(r) : "v"(lo), "v"(hi));
    return r;
}
static __device__ __forceinline__ void swp32(unsigned int& a, unsigned int& b) {
    asm volatile("v_permlane32_swap_b32 %0, %1" : "+v"(a), "+v"(b));
}
static __device__ __forceinline__ float xhalf_max(float v) {
    float a = v, b;
    asm("v_mov_b32 %0, %1" : "=v"(b) : "v"(v));
    asm volatile("v_permlane32_swap_b32 %0, %1" : "+v"(a), "+v"(b));
    return fmaxf(a, b);
}
static __device__ __forceinline__ float xhalf_add(float v) {
    float a = v, b;
    asm("v_mov_b32 %0, %1" : "=v"(b) : "v"(v));
    asm volatile("v_permlane32_swap_b32 %0, %1" : "+v"(a), "+v"(b));
    return a + b;
}
static __device__ __forceinline__ float vtmax(const f32x16& d) {
    return fmaxf(
      fmaxf(fmaxf(fmaxf(d[0],d[1]),fmaxf(d[2],d[3])), fmaxf(fmaxf(d[4],d[5]),fmaxf(d[6],d[7]))),
      fmaxf(fmaxf(fmaxf(d[8],d[9]),fmaxf(d[10],d[11])), fmaxf(fmaxf(d[12],d[13]),fmaxf(d[14],d[15]))));
}
static __device__ __forceinline__ float vtsum(const f32x16& d) {
    return ((((d[0]+d[1])+(d[2]+d[3])) + ((d[4]+d[5])+(d[6]+d[7])))
          + (((d[8]+d[9])+(d[10]+d[11])) + ((d[12]+d[13])+(d[14]+d[15]))));
}

// D-layout (doc-verified): value for (r = lane&31, m = (reg&3)+8*(reg>>2)+4*h).
// Build B-frags where element e of lo/hi holds q[state j = 8h+e (+16)] — the
// SAME (h,e)->k map used for the A-frags, so any k-permutation cancels.
static __device__ __forceinline__ void make_frags(const f32x16& q, short8& lo, short8& hi) {
    unsigned int X  = pkbf(q[0],  q[1]),  Z  = pkbf(q[2],  q[3]);
    unsigned int Y  = pkbf(q[4],  q[5]),  W  = pkbf(q[6],  q[7]);
    unsigned int X2 = pkbf(q[8],  q[9]),  Z2 = pkbf(q[10], q[11]);
    unsigned int Y2 = pkbf(q[12], q[13]), W2 = pkbf(q[14], q[15]);
    swp32(X, Y); swp32(Z, W); swp32(X2, Y2); swp32(Z2, W2);
    union { unsigned int w[4]; short8 s; } u;
    u.w[0] = X;  u.w[1] = Z;  u.w[2] = Y;  u.w[3] = W;  lo = u.s;
    u.w[0] = X2; u.w[1] = Z2; u.w[2] = Y2; u.w[3] = W2; hi = u.s;
}

#define MF_IDS                                                            \
    const int tid  = threadIdx.x;                                         \
    const int w    = tid >> 6;                                            \
    const int lane = tid & 63;                                            \
    const int h    = lane >> 5;                                           \
    const int r    = lane & 31;                                           \
    const int wgid = blockIdx.x * 2 + w;                                  \
    const int chunk = wgid & (MF_NCHUNK - 1);                             \
    const int row0  = (wgid >> 7) << 5;

#define MF_CONSTS                                                         \
    f32x16 muv, c0v, c1v, li2m;                                           \
    _Pragma("unroll")                                                     \
    for (int i = 0; i < 16; ++i) {                                        \
        int m = (i & 3) + ((i >> 2) << 3) + (h << 2);                     \
        float ls = log_sig[m];                                            \
        muv[i]  = means[m];                                               \
        c1v[i]  = -0.5f * expf(-2.0f * ls) * F_LOG2E;                     \
        c0v[i]  = (-ls + F_NEG_HALF_LOG2PI) * F_LOG2E;                    \
        li2m[i] = log_init[m] * F_LOG2E;                                  \
    }

#define MF_AFRAGS                                                         \
    const float* Ar = Amat + r * 32 + (h << 3);                           \
    float4 a0_ = *(const float4*)(Ar),      a1_ = *(const float4*)(Ar + 4);  \
    float4 a2_ = *(const float4*)(Ar + 16), a3_ = *(const float4*)(Ar + 20); \
    short8 alo, ahi;                                                      \
    {                                                                     \
        union { unsigned int ww[4]; short8 s; } ua;                       \
        ua.ww[0] = pkbf(a0_.x, a0_.y); ua.ww[1] = pkbf(a0_.z, a0_.w);     \
        ua.ww[2] = pkbf(a1_.x, a1_.y); ua.ww[3] = pkbf(a1_.z, a1_.w);     \
        alo = ua.s;                                                       \
        ua.ww[0] = pkbf(a2_.x, a2_.y); ua.ww[1] = pkbf(a2_.z, a2_.w);     \
        ua.ww[2] = pkbf(a3_.x, a3_.y); ua.ww[3] = pkbf(a3_.z, a3_.w);     \
        ahi = ua.s;                                                       \
    }

// stage obvs[row0+rr][tbase .. tbase+span) into xsw[t][rr]; tbase % 32 == 0
#define MF_STAGE(xsw, tbase, span)                                        \
    {                                                                     \
        const float* xr_ = obvs + (size_t)(row0 + r) * SEQLEN + (tbase);  \
        for (int tt = 4 * h; tt + 4 <= (span); tt += 8) {                 \
            float4 v_ = *(const float4*)(xr_ + tt);                       \
            xsw[tt + 0][r] = v_.x; xsw[tt + 1][r] = v_.y;                 \
            xsw[tt + 2][r] = v_.z; xsw[tt + 3][r] = v_.w;                 \
        }                                                                 \
        int tail0_ = (span) & ~3;                                         \
        for (int ii = lane; ii < ((span) - tail0_) * 32; ii += 64) {      \
            int tt_ = tail0_ + (ii >> 5), rr_ = ii & 31;                  \
            xsw[tt_][rr_] = obvs[(size_t)(row0 + rr_) * SEQLEN + (tbase) + tt_]; \
        }                                                                 \
        __threadfence_block();                                            \
    }

__global__ __launch_bounds__(128, 1) void hmm_fwd_mf(
    const float* __restrict__ obvs, const float* __restrict__ log_init,
    const float* __restrict__ Amat, const float* __restrict__ means,
    const float* __restrict__ log_sig, float* __restrict__ fdump)
{
    __shared__ float xs[2][MF_SPANF][32];
    MF_IDS;
    const int t0 = chunk * MF_CHUNK, t1 = t0 + MF_CHUNK;
    const int ts = (t0 > MF_HALO_F) ? (t0 - MF_HALO_F) : 0;
    const int span = t1 - ts;   // {32,64,96,128}
    MF_CONSTS; MF_AFRAGS;
    float (*xsw)[32] = xs[w];
    MF_STAGE(xsw, ts, span);

    const f32x16 zro = (f32x16)0.0f;
    f32x16 qh, cur;
    {
        float x0 = xsw[0][r];
#pragma unroll
        for (int i = 0; i < 16; ++i) {
            float dx = x0 - muv[i];
            cur[i] = fmaf(c1v[i] * dx, dx, c0v[i]) + (chunk == 0 ? li2m[i] : 0.0f);
            qh[i] = EXP2F(cur[i]);
        }
        if (chunk == 0)
            *(f32x16*)(fdump + (((size_t)wgid * MF_CHUNK) << 10) + (lane << 4)) = cur;
    }
    for (int t = ts + 1; t < t1; ++t) {
        short8 blo, bhi; make_frags(qh, blo, bhi);
        f32x16 d = __builtin_amdgcn_mfma_f32_32x32x16_bf16(alo, blo, zro, 0, 0, 0);
        d = __builtin_amdgcn_mfma_f32_32x32x16_bf16(ahi, bhi, d, 0, 0, 0);
        float mx = xhalf_max(vtmax(d));
        float rs = RCPF(mx);
        float x = xsw[t - ts][r];
#pragma unroll
        for (int i = 0; i < 16; ++i) {
            float dx = x - muv[i];
            float e2 = fmaf(c1v[i] * dx, dx, c0v[i]);
            qh[i] = d[i] * rs * EXP2F(e2);
        }
        if (t >= t0) {
            f32x16 lg;
#pragma unroll
            for (int i = 0; i < 16; ++i) lg[i] = LOG2F(qh[i]);
            *(f32x16*)(fdump + (((size_t)wgid * MF_CHUNK + (t - t0)) << 10) + (lane << 4)) = lg;
        }
    }
}

__global__ __launch_bounds__(128, 1) void hmm_bwd_mf(
    const float* __restrict__ obvs, const float* __restrict__ log_init,
    const float* __restrict__ Amat, const float* __restrict__ means,
    const float* __restrict__ log_sig, const float* __restrict__ fdump,
    float* __restrict__ out)
{
    __shared__ float xs[2][MF_SPANB][32];
    __shared__ float os[2][32][128];
    MF_IDS;
    const int t0 = chunk * MF_CHUNK, t1 = t0 + MF_CHUNK;
    const bool last = (chunk == MF_NCHUNK - 1);
    const int tsb = last ? (SEQLEN - 1)
                         : ((t1 - 1 + MF_HALO_B < SEQLEN - 1) ? (t1 - 1 + MF_HALO_B) : (SEQLEN - 1));
    const int spanB = tsb - t0 + 1;   // {127, 96, 64, 32}
    MF_CONSTS; MF_AFRAGS;
    float (*xsw)[32] = xs[w];
    MF_STAGE(xsw, t0, spanB);

    const f32x16 zro = (f32x16)0.0f;
    const int xr4 = (r & 7) << 2;

#define COMBINE_OS(TL_, LGB_)                                             \
    {                                                                     \
        f32x16 g_;                                                        \
        _Pragma("unroll")                                                 \
        for (int i_ = 0; i_ < 16; ++i_) g_[i_] = fvv[i_] + (LGB_)[i_];    \
        float mg_ = xhalf_max(vtmax(g_));                                 \
        f32x16 p_;                                                        \
        _Pragma("unroll")                                                 \
        for (int i_ = 0; i_ < 16; ++i_) p_[i_] = EXP2F(g_[i_] - mg_);     \
        float s_ = xhalf_add(vtsum(p_));                                  \
        float z_ = mg_ + LOG2F(s_);                                       \
        _Pragma("unroll")                                                 \
        for (int i_ = 0; i_ < 16; ++i_) g_[i_] = (g_[i_] - z_) * F_LN2;   \
        float* orow_ = &os[w][r][0];                                      \
        int cb_ = (((TL_) & 3) << 5) + (h << 2);                          \
        float4 v0_ = {g_[0],  g_[1],  g_[2],  g_[3]};                     \
        float4 v1_ = {g_[4],  g_[5],  g_[6],  g_[7]};                     \
        float4 v2_ = {g_[8],  g_[9],  g_[10], g_[11]};                    \
        float4 v3_ = {g_[12], g_[13], g_[14], g_[15]};                    \
        *(float4*)(orow_ + ((cb_ + 0)  ^ xr4)) = v0_;                     \
        *(float4*)(orow_ + ((cb_ + 8)  ^ xr4)) = v1_;                     \
        *(float4*)(orow_ + ((cb_ + 16) ^ xr4)) = v2_;                     \
        *(float4*)(orow_ + ((cb_ + 24) ^ xr4)) = v3_;                     \
    }

#define OS_FLUSH(TBASE_)                                                  \
    {                                                                     \
        __threadfence_block();                                            \
        int q_ = lane & 3, r2_ = lane >> 2;                               \
        _Pragma("unroll")                                                 \
        for (int p_ = 0; p_ < 2; ++p_) {                                  \
            int rf_ = p_ * 16 + r2_;                                      \
            const float* orow_ = &os[w][rf_][0];                          \
            float* gb_ = out + (size_t)(row0 + rf_) * (SEQLEN * NSTATES)  \
                             + (size_t)(TBASE_) * NSTATES;                \
            _Pragma("unroll")                                             \
            for (int k_ = 0; k_ < 8; ++k_) {                              \
                int L_ = (k_ << 4) + (q_ << 2);                           \
                *(float4*)(gb_ + L_) =                                    \
                    *(const float4*)(orow_ + (L_ ^ ((rf_ & 7) << 2)));    \
            }                                                             \
        }                                                                 \
    }

    f32x16 bh;
    int tstart;
    if (last) {
        f32x16 fvv = *(const f32x16*)(fdump + (((size_t)wgid * MF_CHUNK + 31) << 10) + (lane << 4));
        COMBINE_OS(31, li2m);
        float lm = xhalf_max(vtmax(li2m));
#pragma unroll
        for (int i = 0; i < 16; ++i) bh[i] = EXP2F(li2m[i] - lm);
        tstart = SEQLEN - 2;
    } else {
#pragma unroll
        for (int i = 0; i < 16; ++i) bh[i] = 1.0f;
        tstart = tsb - 1;
    }

    for (int t = tstart; t >= t0; --t) {
        int tl = t - t0;
        bool store = (tl < MF_CHUNK);
        float x = xsw[t + 1 - t0][r];
        f32x16 fvv;
        if (store)
            fvv = *(const f32x16*)(fdump + (((size_t)wgid * MF_CHUNK + tl) << 10) + (lane << 4));
        f32x16 wv;
#pragma unroll
        for (int i = 0; i < 16; ++i) {
            float dx = x - muv[i];
            float e2 = fmaf(c1v[i] * dx, dx, c0v[i]);
            wv[i] = bh[i] * EXP2F(e2);
        }
        short8 blo, bhi; make_frags(wv, blo, bhi);
        f32x16 d = __builtin_amdgcn_mfma_f32_32x32x16_bf16(alo, blo, zro, 0, 0, 0);
        d = __builtin_amdgcn_mfma_f32_32x32x16_bf16(ahi, bhi, d, 0, 0, 0);
        float mx = xhalf_max(vtmax(d));
        float rs = RCPF(mx);
#pragma unroll
        for (int i = 0; i < 16; ++i) bh[i] = d[i] * rs;
        if (store) {
            f32x16 lgb;
#pragma unroll
            for (int i = 0; i < 16; ++i) lgb[i] = LOG2F(d[i]);
            COMBINE_OS(tl, lgb);
            if ((tl & 3) == 0) OS_FLUSH(t);
        }
    }
#undef COMBINE_OS
#undef OS_FLUSH
}

// ===================== Fallback path (round-4, verified) =====================
#define CHUNK_L 128
#define HALO 96
#define NCHUNKS (SEQLEN / CHUNK_L)
#define WPB 4
#define XBUF_LEN (CHUNK_L + HALO)
#define WAVES_PER_CHUNK (NBATCH / 2)

#define SWZF(x, imm) __int_as_float(__builtin_amdgcn_ds_swizzle(__float_as_int(x), (imm)))

template <int CTRL>
static __device__ __forceinline__ float dppf(float x) {
    return __int_as_float(__builtin_amdgcn_update_dpp(
        0, __float_as_int(x), CTRL, 0xF, 0xF, true));
}
static __device__ __forceinline__ float rmax32(float v) {
    v = fmaxf(v, dppf<0xB1>(v));
    v = fmaxf(v, dppf<0x4E>(v));
    v = fmaxf(v, dppf<0x141>(v));
    v = fmaxf(v, dppf<0x140>(v));
    v = fmaxf(v, SWZF(v, 0x401F));
    return v;
}
static __device__ __forceinline__ float rsum32(float v) {
    v += dppf<0xB1>(v);
    v += dppf<0x4E>(v);
    v += dppf<0x141>(v);
    v += dppf<0x140>(v);
    v += SWZF(v, 0x401F);
    return v;
}

#define MATVEC(qv, uout)                                                  \
    {                                                                     \
        psp[i] = (qv);                                                    \
        __threadfence_block();                                            \
        float ax = 0.f, ay = 0.f, az = 0.f, aw = 0.f;                     \
        _Pragma("unroll")                                                 \
        for (int jj = 0; jj < 8; ++jj) {                                  \
            float4 pv = ps4[jj];                                          \
            ax = fmaf(arow[jj].x, pv.x, ax);                              \
            ay = fmaf(arow[jj].y, pv.y, ay);                              \
            az = fmaf(arow[jj].z, pv.z, az);                              \
            aw = fmaf(arow[jj].w, pv.w, aw);                              \
        }                                                                 \
        __threadfence_block();                                            \
        (uout) = (ax + ay) + (az + aw);                                   \
    }

__global__ __launch_bounds__(WPB * 64) void hmm_fwd(
    const float* __restrict__ obvs, const float* __restrict__ log_init,
    const float* __restrict__ Amat, const float* __restrict__ means,
    const float* __restrict__ log_sig, float* __restrict__ fbuf)
{
    __shared__ float xs[WPB][2][XBUF_LEN];
    __shared__ __align__(16) float ps[WPB][2][NSTATES];
    const int tid = threadIdx.x;
    const int w = tid >> 6, lane = tid & 63, h = lane >> 5, i = lane & 31;
    const int wgid = blockIdx.x * WPB + w;
    const int chunk = wgid >> 7;
    const int row = ((wgid & 127) << 1) | h;
    const int t0 = chunk * CHUNK_L, t1 = t0 + CHUNK_L;
    const int ts = (chunk == 0) ? 0 : t0 - HALO;
    const float mu = means[i], lsig = log_sig[i];
    const float c1 = -0.5f * expf(-2.0f * lsig) * F_LOG2E;
    const float c0 = (-lsig + F_NEG_HALF_LOG2PI) * F_LOG2E;
    const float li2 = log_init[i] * F_LOG2E;
    float4 arow[8];
#pragma unroll
    for (int jj = 0; jj < 8; ++jj)
        arow[jj] = reinterpret_cast<const float4*>(Amat)[i * 8 + jj];
    const float* xr = obvs + (size_t)row * SEQLEN;
    for (int t = ts + i; t < t1; t += 32) xs[w][h][t - ts] = xr[t];
    __syncthreads();
    const float* xp = &xs[w][h][0];
    float* psp = &ps[w][h][0];
    const float4* ps4 = reinterpret_cast<const float4*>(psp);
#define E2(x) ({ float d_ = (x) - mu; fmaf(d_ * d_, c1, c0); })
    float* frow = fbuf + (size_t)row * SEQLEN * NSTATES + i;
    float e0 = E2(xp[0]);
    float q;
    if (chunk == 0) { float v0 = e0 + li2; frow[0] = v0; q = EXP2F(v0); }
    else            { q = EXP2F(e0); }
    for (int t = ts + 1; t < t1; ++t) {
        float u; MATVEC(q, u);
        float r_ = RCPF(SWZF(u, 0x0000));
        float E = EXP2F(E2(xp[t - ts]));
        q = (u * r_) * E;
        if (t >= t0) frow[(size_t)t * NSTATES] = LOG2F(q);
    }
#undef E2
}

__global__ __launch_bounds__(WPB * 64) void hmm_bwd(
    const float* __restrict__ obvs, const float* __restrict__ log_init,
    const float* __restrict__ Amat, const float* __restrict__ means,
    const float* __restrict__ log_sig, float* __restrict__ io)
{
    __shared__ float xs[WPB][2][XBUF_LEN];
    __shared__ __align__(16) float ps[WPB][2][NSTATES];
    const int tid = threadIdx.x;
    const int w = tid >> 6, lane = tid & 63, h = lane >> 5, i = lane & 31;
    const int wgid = blockIdx.x * WPB + w;
    const int chunk = wgid >> 7;
    const int row = ((wgid & 127) << 1) | h;
    const int t0 = chunk * CHUNK_L, t1 = t0 + CHUNK_L;
    const bool lastc = (t1 == SEQLEN);
    const int tsb = lastc ? (SEQLEN - 1) : (t1 - 1 + HALO);
    const int xbase = t0 + 1;
    const float mu = means[i], lsig = log_sig[i];
    const float c1 = -0.5f * expf(-2.0f * lsig) * F_LOG2E;
    const float c0 = (-lsig + F_NEG_HALF_LOG2PI) * F_LOG2E;
    const float li2 = log_init[i] * F_LOG2E;
    float4 arow[8];
#pragma unroll
    for (int jj = 0; jj < 8; ++jj)
        arow[jj] = reinterpret_cast<const float4*>(Amat)[i * 8 + jj];
    const float* xr = obvs + (size_t)row * SEQLEN;
    for (int t = xbase + i; t <= tsb; t += 32) xs[w][h][t - xbase] = xr[t];
    __syncthreads();
    const float* xp = &xs[w][h][0];
    float* psp = &ps[w][h][0];
    const float4* ps4 = reinterpret_cast<const float4*>(psp);
#define E2(x) ({ float d_ = (x) - mu; fmaf(d_ * d_, c1, c0); })
    float* frow = io + (size_t)row * SEQLEN * NSTATES + i;
    float u; int thi;
    if (lastc) {
        float g = frow[(size_t)(SEQLEN - 1) * NSTATES] + li2;
        float m = rmax32(g);
        float s = rsum32(EXP2F(g - m));
        frow[(size_t)(SEQLEN - 1) * NSTATES] = (g - m - LOG2F(s)) * F_LN2;
        u = EXP2F(li2); thi = SEQLEN - 2;
    } else { u = 1.0f; thi = tsb - 1; }
    for (int t = thi; t >= t0; --t) {
        const bool store = (t < t1);
        float fv;
        if (store) fv = frow[(size_t)t * NSTATES];
        float r_ = RCPF(SWZF(u, 0x0000));
        float E = EXP2F(E2(xp[t + 1 - xbase]));
        float q = (u * r_) * E;
        MATVEC(q, u);
        if (store) {
            float g = fv + LOG2F(u);
            float m = rmax32(g);
            float s = rsum32(EXP2F(g - m));
            frow[(size_t)t * NSTATES] = (g - m - LOG2F(s)) * F_LN2;
        }
    }
#undef E2
}

extern "C" void kernel_launch(void* const* d_in, const int* in_sizes, int n_in,
                              void* d_out, int out_size, void* d_ws, size_t ws_size,
                              hipStream_t stream) {
    const float* obvs     = (const float*)d_in[0];
    const float* log_init = (const float*)d_in[1];
    const float* Amat     = (const float*)d_in[2];
    const float* means    = (const float*)d_in[3];
    const float* log_sig  = (const float*)d_in[4];
    float* out = (float*)d_out;

    const size_t need = (size_t)NBATCH * SEQLEN * NSTATES * sizeof(float);  // 134 MB
    if (ws_size >= need) {
        float* fdump = (float*)d_ws;
        hipLaunchKernelGGL(hmm_fwd_mf, dim3(512), dim3(128), 0, stream,
                           obvs, log_init, Amat, means, log_sig, fdump);
        hipLaunchKernelGGL(hmm_bwd_mf, dim3(512), dim3(128), 0, stream,
                           obvs, log_init, Amat, means, log_sig, fdump, out);
    } else {
        dim3 grid(NCHUNKS * WAVES_PER_CHUNK / WPB), block(WPB * 64);
        hipLaunchKernelGGL(hmm_fwd, grid, block, 0, stream,
                           obvs, log_init, Amat, means, log_sig, out);
        hipLaunchKernelGGL(hmm_bwd, grid, block, 0, stream,
                           obvs, log_init, Amat, means, log_sig, out);
    }
}